// Round 16
// baseline (215.094 us; speedup 1.0000x reference)
//
#include <hip/hip_runtime.h>

#define TT   110          // max_seq_len
#define BBD  256          // num dialogues
#define NND  28160        // TT*BBD
#define WIN  10

typedef __bf16 bf16x8 __attribute__((ext_vector_type(8)));
typedef __bf16 bf16x4 __attribute__((ext_vector_type(4)));
typedef float  f32x4  __attribute__((ext_vector_type(4)));

__device__ __forceinline__ int imax(int a, int b){ return a > b ? a : b; }
__device__ __forceinline__ int imin(int a, int b){ return a < b ? a : b; }

// All per-node matrices are SOURCE-MAJOR: row m = t*256 + b  (node n = b*110+t).
// Weight images (bf16, pre-swizzled per 64-col tile, row=col, KSP elems):
//   Wfimg [4][64][320] @ img+0
//   wrimg [9][64][256] @ img+81920   (built from comp x basis inline)
//   Wmaimg[5][64][320] @ img+229376
//   Wlimg [1][64][320] @ img+331776
//   Wgcimg[1][64][128] @ img+352256
// Image storage: source k-chunk c (8 bf16) stored at chunk position c^(col&7).

// ---------------------------------------------------------------------------
// prep_k: (a) pack f32 modalities -> Ain[N][320] bf16 (cols 300..319 zero);
// (b) build all bf16 pre-swizzled weight tile images. RGCN basis expansion
// (Wrels = comp x basis) is computed inline in the wrimg branch.
// ---------------------------------------------------------------------------
__global__ __launch_bounds__(256) void prep_k(
    const float* __restrict__ textf, const float* __restrict__ acouf,
    const float* __restrict__ visuf, const float* __restrict__ basis,
    const float* __restrict__ comp, const float* __restrict__ root,
    const float* __restrict__ Wf, const float* __restrict__ Wma,
    const float* __restrict__ Wl, const float* __restrict__ Wrel,
    const float* __restrict__ Wroot2, __bf16* __restrict__ Ain,
    __bf16* __restrict__ img)
{
  constexpr int T0 = 1126400;            // Ain chunks: N*40
  constexpr int T1 = T0 + 10240;         // Wf   4*64*40
  constexpr int T2 = T1 + 18432;         // wrimg 9*64*32
  constexpr int T3 = T2 + 12800;         // Wma  5*64*40
  constexpr int T4 = T3 + 2560;          // Wl   64*40
  constexpr int T5 = T4 + 1024;          // Wgc  64*16
  for (int c = blockIdx.x * 256 + threadIdx.x; c < T5; c += gridDim.x * 256) {
    bf16x8 v;
    __bf16* dst;
    if (c < T0) {
      const int m = c / 40, cc = c - m * 40;
      const int col0 = cc << 3;
      const size_t ab = (size_t)m * 100;
      #pragma unroll
      for (int e = 0; e < 8; ++e) {
        const int col = col0 + e;
        float x = (col < 100) ? textf[ab + col]
                : (col < 200) ? acouf[ab + col - 100]
                : (col < 300) ? visuf[ab + col - 200] : 0.f;
        v[e] = (__bf16)x;
      }
      dst = Ain + (size_t)m * 320 + col0;
    } else if (c < T1) {
      const int r = c - T0;
      const int cb = r / 2560, r2 = r - cb * 2560;
      const int col = r2 / 40, ch = r2 - col * 40;
      const int cs = (ch & ~7) | ((ch ^ col) & 7);
      const int gc = (cb << 6) + col;
      #pragma unroll
      for (int e = 0; e < 8; ++e) {
        const int k = (cs << 3) + e;
        v[e] = (__bf16)((k < 300 && gc < 200) ? Wf[k*200 + gc] : 0.f);
      }
      dst = img + cb * 20480 + col * 320 + (ch << 3);
    } else if (c < T2) {
      const int r = c - T1;
      const int cb = r >> 11, r2 = r & 2047;       // 2048 chunks per rel block
      const int col = r2 >> 5, ch = r2 & 31;
      const int cs = (ch & ~7) | ((ch ^ col) & 7);
      if (cb < 8) {
        float acc[8] = {0.f,0.f,0.f,0.f,0.f,0.f,0.f,0.f};
        for (int nb = 0; nb < 30; ++nb) {
          const float cmp = comp[cb*30 + nb];
          const float* bp = basis + nb*12800 + col;
          #pragma unroll
          for (int e = 0; e < 8; ++e) {
            const int k = (cs << 3) + e;
            if (k < 200) acc[e] = fmaf(cmp, bp[k*64], acc[e]);
          }
        }
        #pragma unroll
        for (int e = 0; e < 8; ++e) v[e] = (__bf16)acc[e];
      } else {
        #pragma unroll
        for (int e = 0; e < 8; ++e) {
          const int k = (cs << 3) + e;
          v[e] = (__bf16)((k < 200) ? root[k*64 + col] : 0.f);
        }
      }
      dst = img + 81920 + cb * 16384 + col * 256 + (ch << 3);
    } else if (c < T3) {
      const int r = c - T2;
      const int cb = r / 2560, r2 = r - cb * 2560;
      const int col = r2 / 40, ch = r2 - col * 40;
      const int cs = (ch & ~7) | ((ch ^ col) & 7);
      const int gc = (cb << 6) + col;
      #pragma unroll
      for (int e = 0; e < 8; ++e) {
        const int k = (cs << 3) + e;
        v[e] = (__bf16)((k < 264 && gc < 264) ? Wma[k*264 + gc] : 0.f);
      }
      dst = img + 229376 + cb * 20480 + col * 320 + (ch << 3);
    } else if (c < T4) {
      const int r = c - T3;
      const int col = r / 40, ch = r - col * 40;
      const int cs = (ch & ~7) | ((ch ^ col) & 7);
      #pragma unroll
      for (int e = 0; e < 8; ++e) {
        const int k = (cs << 3) + e;
        v[e] = (__bf16)((k < 264) ? Wl[k*64 + col] : 0.f);
      }
      dst = img + 331776 + col * 320 + (ch << 3);
    } else {
      const int r = c - T4;
      const int col = r / 16, ch = r - col * 16;
      const int cs = (ch & ~7) | ((ch ^ col) & 7);
      #pragma unroll
      for (int e = 0; e < 8; ++e) {
        const int k = (cs << 3) + e;
        v[e] = (__bf16)((k < 64) ? Wrel[k*64 + col] : Wroot2[(k-64)*64 + col]);
      }
      dst = img + 352256 + col * 128 + (ch << 3);
    }
    *(bf16x8*)dst = v;
  }
}

// ---------------------------------------------------------------------------
// bgemm: B-resident MFMA GEMM, bf16 A + pre-swizzled B image.
// MODE==1 + spkm: write relation col-block cb only for rows whose source
// speaker matches (cb>>2)==spk[row]; root block (cb==8) always written.
// ---------------------------------------------------------------------------
template<int MODE, int NK, int KSP, int NCB, int OUT>
__global__ __launch_bounds__(256) void bgemm_k(
    const __bf16* __restrict__ A0, const __bf16* __restrict__ A1,
    const __bf16* __restrict__ Bimg, const float* __restrict__ bias,
    void* __restrict__ Cv, int Ncols, const int* __restrict__ spkm)
{
  __shared__ __align__(16) __bf16 Bsh[64][KSP];
  const int tid = threadIdx.x;
  constexpr int NWT = 440 * NCB;
  constexpr int q = NWT >> 3;
  const int bid = blockIdx.x;
  const int w = (bid & 7) * q + (bid >> 3);          // bijective XCD swizzle
  const int m0 = (w / NCB) << 6;
  const int cb = w % NCB;
  const int n0 = cb << 6;

  { // ---- B tile: linear vector copy of pre-swizzled image ----
    const bf16x8* src = (const bf16x8*)(Bimg + (size_t)cb * (64 * KSP));
    bf16x8* dst = (bf16x8*)&Bsh[0][0];
    constexpr int NIT = (64 * KSP / 8) / 256;
    #pragma unroll
    for (int c = 0; c < NIT; ++c) dst[c * 256 + tid] = src[c * 256 + tid];
  }
  __syncthreads();

  const int wid = tid >> 6, lane = tid & 63;
  const int wm = wid >> 1, wn = wid & 1;
  const int fr = lane & 15;
  const int fk = (lane >> 4) << 3;
  const int row0 = (lane >> 4) << 2;

  f32x4 acc[2][2];
  #pragma unroll
  for (int f = 0; f < 2; ++f)
    #pragma unroll
    for (int g = 0; g < 2; ++g) acc[f][g] = (f32x4){0.f,0.f,0.f,0.f};

  #pragma unroll
  for (int kt = 0; kt < NK; ++kt) {
    const int ko = (kt << 5) + fk;
    bf16x8 af[2];
    #pragma unroll
    for (int f = 0; f < 2; ++f) {
      const int ra = m0 + wm*32 + f*16 + fr;
      if constexpr (MODE == 2) {
        af[f] = (ko < 200) ? *(const bf16x8*)(A0 + (size_t)ra*200 + ko)
                           : *(const bf16x8*)(A1 + (size_t)ra*64 + (ko - 200));
      } else {
        constexpr int SA = (MODE == 0) ? 320 : 200;
        af[f] = *(const bf16x8*)(A0 + (size_t)ra*SA + ko);
      }
    }
    bf16x8 bfv[2];
    #pragma unroll
    for (int g = 0; g < 2; ++g) {
      const int rb_ = wn*32 + g*16 + fr;
      bfv[g] = *(const bf16x8*)&Bsh[rb_][(((ko >> 3) ^ (rb_ & 7)) << 3)];
    }
    #pragma unroll
    for (int f = 0; f < 2; ++f)
      #pragma unroll
      for (int g = 0; g < 2; ++g)
        acc[f][g] = __builtin_amdgcn_mfma_f32_16x16x32_bf16(af[f], bfv[g], acc[f][g], 0, 0, 0);
  }

  // ---- epilogue: D col=lane&15, row=(lane>>4)*4+reg ----
  #pragma unroll
  for (int f = 0; f < 2; ++f) {
    const int gm0 = m0 + wm*32 + f*16 + row0;
    int sp[4];
    if constexpr (MODE == 1) {
      #pragma unroll
      for (int r2 = 0; r2 < 4; ++r2) sp[r2] = spkm[gm0 + r2];
    }
    #pragma unroll
    for (int g = 0; g < 2; ++g) {
      const int col = n0 + wn*32 + g*16 + fr;
      if (col < Ncols) {
        const float bv = bias ? bias[col] : 0.f;
        #pragma unroll
        for (int r2 = 0; r2 < 4; ++r2) {
          const float v = acc[f][g][r2] + bv;
          const int gm = gm0 + r2;
          bool dow = true;
          if constexpr (MODE == 1) dow = (cb == 8) || ((cb >> 2) == sp[r2]);
          if (dow) {
            ((__bf16*)Cv)[(size_t)gm * Ncols + col] = (__bf16)v;
          }
        }
      }
    }
  }
}

// ---------------------------------------------------------------------------
// dialog_k: fused RGCN mean-agg + window-sum + GraphConv GEMM (round-14 cfg).
// ---------------------------------------------------------------------------
__global__ __launch_bounds__(512) void dialog_k(
    const __bf16* __restrict__ xr, const int* __restrict__ spk,
    const float* __restrict__ brg, const __bf16* __restrict__ Wgcimg,
    const float* __restrict__ brel, __bf16* __restrict__ h2)
{
  __shared__ __align__(16) __bf16 Xsh[75][320];
  __shared__ float  h1f[65][68];
  __shared__ __align__(16) __bf16 aggbf[56][72];
  __shared__ int ssp[TT];
  __shared__ int pc[TT + 1];
  const int bid = blockIdx.x;
  const int b = bid >> 1, half = bid & 1;
  const int t0   = half ? 55 : 0;
  const int H1LO = half ? 45 : 0;
  const int XLO  = half ? 35 : 0;
  const int tid = threadIdx.x;
  if (tid < TT) ssp[tid] = spk[tid * BBD + b];
  __syncthreads();
  if (tid < 64) {
    int v = (tid < TT) ? ssp[tid] : 0;
    #pragma unroll
    for (int o = 1; o < 64; o <<= 1) { const int u = __shfl_up(v, o); if (tid >= o) v += u; }
    pc[tid + 1] = v;
    const int tot = __shfl(v, 63);
    int v2 = (tid + 64 < TT) ? ssp[tid + 64] : 0;
    #pragma unroll
    for (int o = 1; o < 64; o <<= 1) { const int u = __shfl_up(v2, o); if (tid >= o) v2 += u; }
    if (tid + 64 < TT) pc[tid + 65] = tot + v2;
    if (tid == 0) pc[0] = 0;
  }
  for (int i = tid << 3; i < 75 * 320; i += 512 << 3) {
    const int xl = i / 320, off = i - xl * 320;
    const int j = XLO + xl;
    const size_t base = ((size_t)j * BBD + b) * 576;
    const int col = (off < 256) ? ((ssp[j] << 8) + off) : (256 + off);
    *(bf16x8*)&Xsh[xl][off] = *(const bf16x8*)&xr[base + col];
  }
  __syncthreads();
  const int w8 = tid >> 6, lane = tid & 63;
  const float bias = brg[lane];
  for (int lh = w8; lh < 65; lh += 8) {
    const int t = H1LO + lh;
    const int si2 = ssp[t] << 1;
    const int jlo = imax(t - WIN, 0), jhi = imin(t + WIN, TT - 1);
    const int n1d0 = pc[t] - pc[jlo];
    const int n0d0 = (t - jlo) - n1d0;
    const int n1d1 = pc[jhi + 1] - pc[t];
    const int n0d1 = (jhi - t + 1) - n1d1;
    const float r00 = 1.f / (float)imax(n0d0, 1);
    const float r10 = 1.f / (float)imax(n1d0, 1);
    const float r01 = 1.f / (float)imax(n0d1, 1);
    const float r11 = 1.f / (float)imax(n1d1, 1);
    float a = 0.f;
    if (t >= WIN && t < TT - WIN) {
      #pragma unroll
      for (int dj = -WIN; dj <= WIN; ++dj) {
        const int j = t + dj;
        const float v = (float)Xsh[j - XLO][((si2 + ((dj >= 0) ? 1 : 0)) << 6) + lane];
        const float w = (dj >= 0) ? (ssp[j] ? r11 : r01) : (ssp[j] ? r10 : r00);
        a = fmaf(w, v, a);
      }
    } else {
      #pragma unroll
      for (int dj = -WIN; dj <= WIN; ++dj) {
        const int j = t + dj;
        const int jc = imin(imax(j, XLO), XLO + 74);
        const float v = (float)Xsh[jc - XLO][((si2 + ((dj >= 0) ? 1 : 0)) << 6) + lane];
        float w = (dj >= 0) ? (ssp[jc] ? r11 : r01) : (ssp[jc] ? r10 : r00);
        if (j < 0 || j >= TT) w = 0.f;
        a = fmaf(w, v, a);
      }
    }
    a += (float)Xsh[t - XLO][256 + lane] + bias;
    h1f[lh][lane] = a;
  }
  __syncthreads();
  for (int lt = w8; lt < 55; lt += 8) {
    const int t = t0 + lt;
    float a = 0.f;
    if (t >= WIN && t < TT - WIN) {
      #pragma unroll
      for (int dj = -WIN; dj <= WIN; ++dj)
        a += h1f[t + dj - H1LO][lane];
    } else {
      #pragma unroll
      for (int dj = -WIN; dj <= WIN; ++dj) {
        const int j = t + dj;
        const int jc = imin(imax(j, H1LO), H1LO + 64);
        const float m = ((j >= 0) && (j < TT)) ? 1.f : 0.f;
        a = fmaf(m, h1f[jc - H1LO][lane], a);
      }
    }
    aggbf[lt][lane] = (__bf16)a;
  }
  __syncthreads();
  if (w8 < 4) {
    const int wm = w8 >> 1, wn = w8 & 1;
    const int fr = lane & 15, fk = (lane >> 4) << 3, row0 = (lane >> 4) << 2;
    const int lhh = t0 - H1LO;
    f32x4 acc[2][2];
    #pragma unroll
    for (int f = 0; f < 2; ++f)
      #pragma unroll
      for (int g = 0; g < 2; ++g) acc[f][g] = (f32x4){0.f,0.f,0.f,0.f};
    #pragma unroll
    for (int kt = 0; kt < 4; ++kt) {
      const int ko = (kt << 5) + fk;
      bf16x8 af[2];
      #pragma unroll
      for (int f = 0; f < 2; ++f) {
        const int tr = wm*32 + f*16 + fr;
        if (tr < 55) {
          if (ko < 64) {
            af[f] = *(const bf16x8*)&aggbf[tr][ko];
          } else {
            const float* src = &h1f[tr + lhh][ko - 64];
            const float4 u0 = ((const float4*)src)[0];
            const float4 u1 = ((const float4*)src)[1];
            af[f] = (bf16x8){(__bf16)u0.x,(__bf16)u0.y,(__bf16)u0.z,(__bf16)u0.w,
                             (__bf16)u1.x,(__bf16)u1.y,(__bf16)u1.z,(__bf16)u1.w};
          }
        } else af[f] = (bf16x8){0,0,0,0,0,0,0,0};
      }
      bf16x8 bfv[2];
      #pragma unroll
      for (int g = 0; g < 2; ++g) {
        const int rb_ = wn*32 + g*16 + fr;
        bfv[g] = *(const bf16x8*)(Wgcimg + rb_*128 + (((ko >> 3) ^ (rb_ & 7)) << 3));
      }
      #pragma unroll
      for (int f = 0; f < 2; ++f)
        #pragma unroll
        for (int g = 0; g < 2; ++g)
          acc[f][g] = __builtin_amdgcn_mfma_f32_16x16x32_bf16(af[f], bfv[g], acc[f][g], 0, 0, 0);
    }
    #pragma unroll
    for (int g = 0; g < 2; ++g) {
      const int col = wn*32 + g*16 + fr;
      const float bv = brel[col];
      #pragma unroll
      for (int f = 0; f < 2; ++f) {
        const int tr0 = wm*32 + f*16 + row0;
        #pragma unroll
        for (int r2 = 0; r2 < 4; ++r2) {
          const int tr = tr0 + r2;
          if (tr < 55) {
            const int t = t0 + tr;
            h2[((size_t)t * BBD + b) * 64 + col] = (__bf16)(acc[f][g][r2] + bv);
          }
        }
      }
    }
  }
}

// ---------------------------------------------------------------------------
// attn_fused: MFMA matching attention + hidden GEMM + logits + log_softmax.
// Single bf16 Xq plane (stride 264). att never leaves LDS.
// ---------------------------------------------------------------------------
__global__ __launch_bounds__(448) void attn_fused_k(
    const __bf16* __restrict__ x, const __bf16* __restrict__ h2,
    const __bf16* __restrict__ Xq, const __bf16* __restrict__ Wlimg,
    const float* __restrict__ bl, const float* __restrict__ Wsm,
    const float* __restrict__ bsm, float* __restrict__ out)
{
  __shared__ __align__(16) __bf16 Msh [TT ][272];
  __shared__ __align__(16) __bf16 MTsh[264][136];
  __shared__ __align__(16) __bf16 Ash [112][136];
  const int b = blockIdx.x;
  const int tid = threadIdx.x;

  for (int idx = tid; idx < TT * 66; idx += 448) {
    const int s = idx / 66, c4 = idx % 66;
    const size_t node = (size_t)s * BBD + b;
    bf16x4 pk;
    if (c4 < 50) pk = *(const bf16x4*)&x [node * 200 + (c4 << 2)];
    else         pk = *(const bf16x4*)&h2[node * 64 + ((c4 - 50) << 2)];
    *(bf16x4*)&Msh[s][c4 << 2] = pk;
    const int d = c4 << 2;
    MTsh[d+0][s] = pk[0]; MTsh[d+1][s] = pk[1];
    MTsh[d+2][s] = pk[2]; MTsh[d+3][s] = pk[3];
  }
  for (int idx = tid; idx < 264 * 26; idx += 448) MTsh[idx / 26][110 + idx % 26] = (__bf16)0.f;
  for (int idx = tid; idx < 112 * 24; idx += 448) Ash[idx / 24][112 + idx % 24] = (__bf16)0.f;
  __syncthreads();

  const int wid = tid >> 6, lane = tid & 63;
  const int t0 = wid << 4;
  const int fr = lane & 15;
  const int g  = lane >> 4;
  const int fk = g << 3;
  const int row0 = g << 2;

  // ---- S = Xq * M^T (single bf16 plane) ----
  f32x4 sacc[7];
  #pragma unroll
  for (int st = 0; st < 7; ++st) sacc[st] = (f32x4){0.f,0.f,0.f,0.f};
  const int trow = t0 + fr;
  const size_t arow = ((size_t)(trow < TT ? trow : TT - 1) * BBD + b) * 264;
  for (int kst = 0; kst < 9; ++kst) {
    const int k0 = kst << 5;
    bf16x8 aq;
    if (kst < 8 || fk == 0) aq = *(const bf16x8*)&Xq[arow + k0 + fk];
    else aq = (bf16x8){0,0,0,0,0,0,0,0};
    #pragma unroll
    for (int st = 0; st < 7; ++st) {
      bf16x8 bq;
      if (kst < 8) bq = *(const bf16x8*)&Msh[st*16 + fr][k0 + fk];
      else bq = (fk == 0) ? *(const bf16x8*)&Msh[st*16 + fr][256]
                          : (bf16x8){0,0,0,0,0,0,0,0};
      sacc[st] = __builtin_amdgcn_mfma_f32_16x16x32_bf16(aq, bq, sacc[st], 0, 0, 0);
    }
  }

  // ---- tanh + softmax -> Ash ----
  #pragma unroll
  for (int r = 0; r < 4; ++r) {
    float tv[7];
    #pragma unroll
    for (int st = 0; st < 7; ++st) {
      const float e2 = __expf(2.f * sacc[st][r]);
      tv[st] = 1.f - 2.f / (e2 + 1.f);
    }
    if (fr >= 14) tv[6] = -3.0e38f;
    float mx = fmaxf(fmaxf(fmaxf(tv[0],tv[1]), fmaxf(tv[2],tv[3])),
                     fmaxf(fmaxf(tv[4],tv[5]), tv[6]));
    #pragma unroll
    for (int o = 8; o >= 1; o >>= 1) mx = fmaxf(mx, __shfl_xor(mx, o, 16));
    float e[7], sum = 0.f;
    #pragma unroll
    for (int st = 0; st < 7; ++st) { e[st] = __expf(tv[st] - mx); sum += e[st]; }
    #pragma unroll
    for (int o = 8; o >= 1; o >>= 1) sum += __shfl_xor(sum, o, 16);
    const float inv = 1.f / sum;
    const int tr = t0 + (g << 2) + r;
    #pragma unroll
    for (int st = 0; st < 7; ++st) Ash[tr][st*16 + fr] = (__bf16)(e[st] * inv);
  }
  __syncthreads();     // all Msh reads done; Ash ready

  // ---- PV: att = alpha * M -> attsh (overlays Msh) ----
  __bf16 (*attsh)[272] = Msh;
  const int tr2 = t0 + (g << 2);
  for (int dt = 0; dt < 17; ++dt) {
    const int d0 = dt << 4;
    f32x4 pacc = (f32x4){0.f,0.f,0.f,0.f};
    #pragma unroll
    for (int kst = 0; kst < 4; ++kst) {
      const int k0 = kst << 5;
      const bf16x8 pa = *(const bf16x8*)&Ash [t0 + fr][k0 + fk];
      const bf16x8 pb = *(const bf16x8*)&MTsh[d0 + fr][k0 + fk];
      pacc = __builtin_amdgcn_mfma_f32_16x16x32_bf16(pa, pb, pacc, 0, 0, 0);
    }
    const int col = d0 + fr;
    if (col < 264) {
      #pragma unroll
      for (int r = 0; r < 4; ++r) {
        const int t = tr2 + r;
        if (t < TT) attsh[t][col] = (__bf16)pacc[r];
      }
    }
  }
  __syncthreads();     // attsh complete; MTsh/Ash now dead

  // ---- stage Wsm into MTsh region ----
  float* Wssh = (float*)&MTsh[0][0];     // [64][8] f32 = 2 KB
  for (int i = tid; i < 512; i += 448) {
    const int k = i >> 3, cc = i & 7;
    Wssh[(k << 3) + cc] = (cc < 7) ? Wsm[k*7 + cc] : 0.f;
  }

  // ---- hidden = relu(att @ Wl + bl), per wave 16 rows x 64 cols ----
  float (*hidf)[68] = (float(*)[68])&Ash[0][0];
  f32x4 hacc[4];
  #pragma unroll
  for (int gg = 0; gg < 4; ++gg) hacc[gg] = (f32x4){0.f,0.f,0.f,0.f};
  #pragma unroll
  for (int kst = 0; kst < 9; ++kst) {
    const int ko = (kst << 5) + fk;
    const int ar = t0 + fr;
    bf16x8 af;
    if (ko < 264 && ar < TT) af = *(const bf16x8*)&attsh[ar][ko];
    else af = (bf16x8){0,0,0,0,0,0,0,0};
    #pragma unroll
    for (int gg = 0; gg < 4; ++gg) {
      const int rb_ = gg*16 + fr;
      const bf16x8 bfv = *(const bf16x8*)(Wlimg + rb_*320 + (((ko >> 3) ^ (rb_ & 7)) << 3));
      hacc[gg] = __builtin_amdgcn_mfma_f32_16x16x32_bf16(af, bfv, hacc[gg], 0, 0, 0);
    }
  }
  #pragma unroll
  for (int gg = 0; gg < 4; ++gg) {
    const int col = gg*16 + fr;
    const float bv = bl[col];
    #pragma unroll
    for (int r = 0; r < 4; ++r) {
      const int row = t0 + row0 + r;
      if (row < TT) hidf[row][col] = fmaxf(hacc[gg][r] + bv, 0.f);
    }
  }
  __syncthreads();

  // ---- logits + log_softmax: 8 lanes per row ----
  const int c = tid & 7;
  const float bc = (c < 7) ? bsm[c] : 0.f;
  #pragma unroll
  for (int p = 0; p < 2; ++p) {
    const int lr = p * 56 + (tid >> 3);
    if (lr < TT) {
      float lg = -3.0e38f;
      if (c < 7) {
        lg = bc;
        #pragma unroll
        for (int k = 0; k < 64; ++k) lg += hidf[lr][k] * Wssh[(k << 3) + c];
      }
      float mx = lg;
      #pragma unroll
      for (int o = 4; o >= 1; o >>= 1) mx = fmaxf(mx, __shfl_xor(mx, o, 8));
      float e = (c < 7) ? __expf(lg - mx) : 0.f;
      float sm = e;
      #pragma unroll
      for (int o = 4; o >= 1; o >>= 1) sm += __shfl_xor(sm, o, 8);
      if (c < 7) out[((size_t)b * TT + lr) * 7 + c] = lg - mx - __logf(sm);
    }
  }
}

// ---------------------------------------------------------------------------
extern "C" void kernel_launch(void* const* d_in, const int* in_sizes, int n_in,
                              void* d_out, int out_size, void* d_ws, size_t ws_size,
                              hipStream_t stream)
{
  const float* textf  = (const float*)d_in[0];
  const float* acouf  = (const float*)d_in[1];
  const float* visuf  = (const float*)d_in[2];
  const int*   spk    = (const int*)  d_in[3];
  const float* Wf     = (const float*)d_in[4];
  const float* bfv    = (const float*)d_in[5];
  const float* basis  = (const float*)d_in[6];
  const float* comp   = (const float*)d_in[7];
  const float* root   = (const float*)d_in[8];
  const float* brg    = (const float*)d_in[9];
  const float* Wrel   = (const float*)d_in[10];
  const float* brel   = (const float*)d_in[11];
  const float* Wroot2 = (const float*)d_in[12];
  const float* Wma    = (const float*)d_in[13];
  const float* bma    = (const float*)d_in[14];
  const float* Wl     = (const float*)d_in[15];
  const float* bl     = (const float*)d_in[16];
  const float* Wsm    = (const float*)d_in[17];
  const float* bsm    = (const float*)d_in[18];

  float* ws = (float*)d_ws;
  __bf16* img   = (__bf16*)(ws + 115200);           // 360,448 bf16 images
  __bf16* Ain   = (__bf16*)(ws + 295424);           // N*320 bf16
  __bf16* xb    = (__bf16*)(ws + 4801024);          // N*200 bf16
  __bf16* xr    = (__bf16*)(ws + 7617024);          // N*576 bf16
  __bf16* h2    = (__bf16*)(ws + 15727104);         // N*64 bf16
  __bf16* Xqb   = (__bf16*)(ws + 16628224);         // N*264 bf16
  float*  outp  = (float*)d_out;

  __bf16* Wfimg  = img;
  __bf16* wrimg  = img + 81920;
  __bf16* Wmaimg = img + 229376;
  __bf16* Wlimg  = img + 331776;
  __bf16* Wgcimg = img + 352256;

  prep_k<<<2048, 256, 0, stream>>>(textf, acouf, visuf, basis, comp, root,
                                   Wf, Wma, Wl, Wrel, Wroot2, Ain, img);
  bgemm_k<0,10,320,4,1><<<1760, 256, 0, stream>>>(Ain, nullptr, Wfimg, bfv, xb, 200, nullptr);
  bgemm_k<1,7,256,9,1><<<3960, 256, 0, stream>>>(xb, nullptr, wrimg, nullptr, xr, 576, spk);
  dialog_k<<<512, 512, 0, stream>>>(xr, spk, brg, Wgcimg, brel, h2);
  bgemm_k<2,9,320,5,1><<<2200, 256, 0, stream>>>(xb, h2, Wmaimg, bma, Xqb, 264, nullptr);
  attn_fused_k<<<256, 448, 0, stream>>>(xb, h2, Xqb, Wlimg, bl, Wsm, bsm, outp);
}

// Round 17
// 147.547 us; speedup vs baseline: 1.4578x; 1.4578x over previous
//
#include <hip/hip_runtime.h>

#define TT   110          // max_seq_len
#define BBD  256          // num dialogues
#define NND  28160        // TT*BBD
#define WIN  10

typedef __bf16 bf16x8 __attribute__((ext_vector_type(8)));
typedef __bf16 bf16x4 __attribute__((ext_vector_type(4)));
typedef float  f32x4  __attribute__((ext_vector_type(4)));

__device__ __forceinline__ int imax(int a, int b){ return a > b ? a : b; }
__device__ __forceinline__ int imin(int a, int b){ return a < b ? a : b; }

// All per-node matrices are SOURCE-MAJOR: row m = t*256 + b  (node n = b*110+t).
// Weight images (bf16, pre-swizzled per 64-col tile, row=col, KSP elems):
//   Wfimg [4][64][320] @ img+0
//   wrimg [9][64][256] @ img+81920
//   Wmaimg[5][64][320] @ img+229376
//   Wlimg [1][64][320] @ img+331776
//   Wgcimg[1][64][128] @ img+352256
// Image storage: source k-chunk c (8 bf16) stored at chunk position c^(col&7).

// ---------------------------------------------------------------------------
// K0: Wrels[r][f][h] = sum_nb comp[r][nb]*basis[nb][f][h]  (r<8); Wrels[8]=root
// (kept as a separate coalesced pass — inlining into prep_k was a 16x
//  regression in round 16: scattered 256B-stride loads, register-starved)
// ---------------------------------------------------------------------------
__global__ __launch_bounds__(256) void wrels_k(
    const float* __restrict__ basis, const float* __restrict__ comp,
    const float* __restrict__ root, float* __restrict__ wrels)
{
  int idx = blockIdx.x * 256 + threadIdx.x;        // 9*12800 = 115200
  if (idx >= 115200) return;
  int r = idx / 12800, fh = idx % 12800;
  float v;
  if (r < 8) {
    v = 0.f;
    #pragma unroll
    for (int nb = 0; nb < 30; ++nb) v += comp[r*30 + nb] * basis[nb*12800 + fh];
  } else {
    v = root[fh];
  }
  wrels[idx] = v;
}

// ---------------------------------------------------------------------------
// prep_k: (a) pack f32 modalities -> Ain[N][320] bf16 (cols 300..319 zero);
// (b) build all bf16 pre-swizzled weight tile images (wrels precomputed).
// ---------------------------------------------------------------------------
__global__ __launch_bounds__(256) void prep_k(
    const float* __restrict__ textf, const float* __restrict__ acouf,
    const float* __restrict__ visuf, const float* __restrict__ wrels,
    const float* __restrict__ Wf, const float* __restrict__ Wma,
    const float* __restrict__ Wl, const float* __restrict__ Wrel,
    const float* __restrict__ Wroot2, __bf16* __restrict__ Ain,
    __bf16* __restrict__ img)
{
  constexpr int T0 = 1126400;            // Ain chunks: N*40
  constexpr int T1 = T0 + 10240;         // Wf   4*64*40
  constexpr int T2 = T1 + 18432;         // wrels 9*64*32
  constexpr int T3 = T2 + 12800;         // Wma  5*64*40
  constexpr int T4 = T3 + 2560;          // Wl   64*40
  constexpr int T5 = T4 + 1024;          // Wgc  64*16
  for (int c = blockIdx.x * 256 + threadIdx.x; c < T5; c += gridDim.x * 256) {
    bf16x8 v;
    __bf16* dst;
    if (c < T0) {
      const int m = c / 40, cc = c - m * 40;
      const int col0 = cc << 3;
      const size_t ab = (size_t)m * 100;
      #pragma unroll
      for (int e = 0; e < 8; ++e) {
        const int col = col0 + e;
        float x = (col < 100) ? textf[ab + col]
                : (col < 200) ? acouf[ab + col - 100]
                : (col < 300) ? visuf[ab + col - 200] : 0.f;
        v[e] = (__bf16)x;
      }
      dst = Ain + (size_t)m * 320 + col0;
    } else if (c < T1) {
      const int r = c - T0;
      const int cb = r / 2560, r2 = r - cb * 2560;
      const int col = r2 / 40, ch = r2 - col * 40;
      const int cs = (ch & ~7) | ((ch ^ col) & 7);
      const int gc = (cb << 6) + col;
      #pragma unroll
      for (int e = 0; e < 8; ++e) {
        const int k = (cs << 3) + e;
        v[e] = (__bf16)((k < 300 && gc < 200) ? Wf[k*200 + gc] : 0.f);
      }
      dst = img + cb * 20480 + col * 320 + (ch << 3);
    } else if (c < T2) {
      const int r = c - T1;
      const int cb = r >> 11, r2 = r & 2047;
      const int col = r2 >> 5, ch = r2 & 31;
      const int cs = (ch & ~7) | ((ch ^ col) & 7);
      #pragma unroll
      for (int e = 0; e < 8; ++e) {
        const int k = (cs << 3) + e;
        v[e] = (__bf16)((k < 200) ? wrels[cb*12800 + k*64 + col] : 0.f);
      }
      dst = img + 81920 + cb * 16384 + col * 256 + (ch << 3);
    } else if (c < T3) {
      const int r = c - T2;
      const int cb = r / 2560, r2 = r - cb * 2560;
      const int col = r2 / 40, ch = r2 - col * 40;
      const int cs = (ch & ~7) | ((ch ^ col) & 7);
      const int gc = (cb << 6) + col;
      #pragma unroll
      for (int e = 0; e < 8; ++e) {
        const int k = (cs << 3) + e;
        v[e] = (__bf16)((k < 264 && gc < 264) ? Wma[k*264 + gc] : 0.f);
      }
      dst = img + 229376 + cb * 20480 + col * 320 + (ch << 3);
    } else if (c < T4) {
      const int r = c - T3;
      const int col = r / 40, ch = r - col * 40;
      const int cs = (ch & ~7) | ((ch ^ col) & 7);
      #pragma unroll
      for (int e = 0; e < 8; ++e) {
        const int k = (cs << 3) + e;
        v[e] = (__bf16)((k < 264) ? Wl[k*64 + col] : 0.f);
      }
      dst = img + 331776 + col * 320 + (ch << 3);
    } else {
      const int r = c - T4;
      const int col = r / 16, ch = r - col * 16;
      const int cs = (ch & ~7) | ((ch ^ col) & 7);
      #pragma unroll
      for (int e = 0; e < 8; ++e) {
        const int k = (cs << 3) + e;
        v[e] = (__bf16)((k < 64) ? Wrel[k*64 + col] : Wroot2[(k-64)*64 + col]);
      }
      dst = img + 352256 + col * 128 + (ch << 3);
    }
    *(bf16x8*)dst = v;
  }
}

// ---------------------------------------------------------------------------
// bgemm: B-resident MFMA GEMM, bf16 A + pre-swizzled B image.
// MODE==1 + spkm: write relation col-block cb only for rows whose source
// speaker matches (cb>>2)==spk[row]; root block (cb==8) always written.
// ---------------------------------------------------------------------------
template<int MODE, int NK, int KSP, int NCB>
__global__ __launch_bounds__(256) void bgemm_k(
    const __bf16* __restrict__ A0, const __bf16* __restrict__ A1,
    const __bf16* __restrict__ Bimg, const float* __restrict__ bias,
    __bf16* __restrict__ Cv, int Ncols, const int* __restrict__ spkm)
{
  __shared__ __align__(16) __bf16 Bsh[64][KSP];
  const int tid = threadIdx.x;
  constexpr int NWT = 440 * NCB;
  constexpr int q = NWT >> 3;
  const int bid = blockIdx.x;
  const int w = (bid & 7) * q + (bid >> 3);          // bijective XCD swizzle
  const int m0 = (w / NCB) << 6;
  const int cb = w % NCB;
  const int n0 = cb << 6;

  { // ---- B tile: linear vector copy of pre-swizzled image ----
    const bf16x8* src = (const bf16x8*)(Bimg + (size_t)cb * (64 * KSP));
    bf16x8* dst = (bf16x8*)&Bsh[0][0];
    constexpr int NIT = (64 * KSP / 8) / 256;
    #pragma unroll
    for (int c = 0; c < NIT; ++c) dst[c * 256 + tid] = src[c * 256 + tid];
  }
  __syncthreads();

  const int wid = tid >> 6, lane = tid & 63;
  const int wm = wid >> 1, wn = wid & 1;
  const int fr = lane & 15;
  const int fk = (lane >> 4) << 3;
  const int row0 = (lane >> 4) << 2;

  f32x4 acc[2][2];
  #pragma unroll
  for (int f = 0; f < 2; ++f)
    #pragma unroll
    for (int g = 0; g < 2; ++g) acc[f][g] = (f32x4){0.f,0.f,0.f,0.f};

  #pragma unroll
  for (int kt = 0; kt < NK; ++kt) {
    const int ko = (kt << 5) + fk;
    bf16x8 af[2];
    #pragma unroll
    for (int f = 0; f < 2; ++f) {
      const int ra = m0 + wm*32 + f*16 + fr;
      if constexpr (MODE == 2) {
        af[f] = (ko < 200) ? *(const bf16x8*)(A0 + (size_t)ra*200 + ko)
                           : *(const bf16x8*)(A1 + (size_t)ra*64 + (ko - 200));
      } else {
        constexpr int SA = (MODE == 0) ? 320 : 200;
        af[f] = *(const bf16x8*)(A0 + (size_t)ra*SA + ko);
      }
    }
    bf16x8 bfv[2];
    #pragma unroll
    for (int g = 0; g < 2; ++g) {
      const int rb_ = wn*32 + g*16 + fr;
      bfv[g] = *(const bf16x8*)&Bsh[rb_][(((ko >> 3) ^ (rb_ & 7)) << 3)];
    }
    #pragma unroll
    for (int f = 0; f < 2; ++f)
      #pragma unroll
      for (int g = 0; g < 2; ++g)
        acc[f][g] = __builtin_amdgcn_mfma_f32_16x16x32_bf16(af[f], bfv[g], acc[f][g], 0, 0, 0);
  }

  // ---- epilogue: D col=lane&15, row=(lane>>4)*4+reg ----
  #pragma unroll
  for (int f = 0; f < 2; ++f) {
    const int gm0 = m0 + wm*32 + f*16 + row0;
    int sp[4];
    if constexpr (MODE == 1) {
      #pragma unroll
      for (int r2 = 0; r2 < 4; ++r2) sp[r2] = spkm[gm0 + r2];
    }
    #pragma unroll
    for (int g = 0; g < 2; ++g) {
      const int col = n0 + wn*32 + g*16 + fr;
      if (col < Ncols) {
        const float bv = bias ? bias[col] : 0.f;
        #pragma unroll
        for (int r2 = 0; r2 < 4; ++r2) {
          const float v = acc[f][g][r2] + bv;
          const int gm = gm0 + r2;
          bool dow = true;
          if constexpr (MODE == 1) dow = (cb == 8) || ((cb >> 2) == sp[r2]);
          if (dow) Cv[(size_t)gm * Ncols + col] = (__bf16)v;
        }
      }
    }
  }
}

// ---------------------------------------------------------------------------
// dialog_k: fused RGCN mean-agg + window-sum + GraphConv GEMM (round-14 cfg).
// ---------------------------------------------------------------------------
__global__ __launch_bounds__(512) void dialog_k(
    const __bf16* __restrict__ xr, const int* __restrict__ spk,
    const float* __restrict__ brg, const __bf16* __restrict__ Wgcimg,
    const float* __restrict__ brel, __bf16* __restrict__ h2)
{
  __shared__ __align__(16) __bf16 Xsh[75][320];
  __shared__ float  h1f[65][68];
  __shared__ __align__(16) __bf16 aggbf[56][72];
  __shared__ int ssp[TT];
  __shared__ int pc[TT + 1];
  const int bid = blockIdx.x;
  const int b = bid >> 1, half = bid & 1;
  const int t0   = half ? 55 : 0;
  const int H1LO = half ? 45 : 0;
  const int XLO  = half ? 35 : 0;
  const int tid = threadIdx.x;
  if (tid < TT) ssp[tid] = spk[tid * BBD + b];
  __syncthreads();
  if (tid < 64) {
    int v = (tid < TT) ? ssp[tid] : 0;
    #pragma unroll
    for (int o = 1; o < 64; o <<= 1) { const int u = __shfl_up(v, o); if (tid >= o) v += u; }
    pc[tid + 1] = v;
    const int tot = __shfl(v, 63);
    int v2 = (tid + 64 < TT) ? ssp[tid + 64] : 0;
    #pragma unroll
    for (int o = 1; o < 64; o <<= 1) { const int u = __shfl_up(v2, o); if (tid >= o) v2 += u; }
    if (tid + 64 < TT) pc[tid + 65] = tot + v2;
    if (tid == 0) pc[0] = 0;
  }
  for (int i = tid << 3; i < 75 * 320; i += 512 << 3) {
    const int xl = i / 320, off = i - xl * 320;
    const int j = XLO + xl;
    const size_t base = ((size_t)j * BBD + b) * 576;
    const int col = (off < 256) ? ((ssp[j] << 8) + off) : (256 + off);
    *(bf16x8*)&Xsh[xl][off] = *(const bf16x8*)&xr[base + col];
  }
  __syncthreads();
  const int w8 = tid >> 6, lane = tid & 63;
  const float bias = brg[lane];
  for (int lh = w8; lh < 65; lh += 8) {
    const int t = H1LO + lh;
    const int si2 = ssp[t] << 1;
    const int jlo = imax(t - WIN, 0), jhi = imin(t + WIN, TT - 1);
    const int n1d0 = pc[t] - pc[jlo];
    const int n0d0 = (t - jlo) - n1d0;
    const int n1d1 = pc[jhi + 1] - pc[t];
    const int n0d1 = (jhi - t + 1) - n1d1;
    const float r00 = 1.f / (float)imax(n0d0, 1);
    const float r10 = 1.f / (float)imax(n1d0, 1);
    const float r01 = 1.f / (float)imax(n0d1, 1);
    const float r11 = 1.f / (float)imax(n1d1, 1);
    float a = 0.f;
    if (t >= WIN && t < TT - WIN) {
      #pragma unroll
      for (int dj = -WIN; dj <= WIN; ++dj) {
        const int j = t + dj;
        const float v = (float)Xsh[j - XLO][((si2 + ((dj >= 0) ? 1 : 0)) << 6) + lane];
        const float w = (dj >= 0) ? (ssp[j] ? r11 : r01) : (ssp[j] ? r10 : r00);
        a = fmaf(w, v, a);
      }
    } else {
      #pragma unroll
      for (int dj = -WIN; dj <= WIN; ++dj) {
        const int j = t + dj;
        const int jc = imin(imax(j, XLO), XLO + 74);
        const float v = (float)Xsh[jc - XLO][((si2 + ((dj >= 0) ? 1 : 0)) << 6) + lane];
        float w = (dj >= 0) ? (ssp[jc] ? r11 : r01) : (ssp[jc] ? r10 : r00);
        if (j < 0 || j >= TT) w = 0.f;
        a = fmaf(w, v, a);
      }
    }
    a += (float)Xsh[t - XLO][256 + lane] + bias;
    h1f[lh][lane] = a;
  }
  __syncthreads();
  for (int lt = w8; lt < 55; lt += 8) {
    const int t = t0 + lt;
    float a = 0.f;
    if (t >= WIN && t < TT - WIN) {
      #pragma unroll
      for (int dj = -WIN; dj <= WIN; ++dj)
        a += h1f[t + dj - H1LO][lane];
    } else {
      #pragma unroll
      for (int dj = -WIN; dj <= WIN; ++dj) {
        const int j = t + dj;
        const int jc = imin(imax(j, H1LO), H1LO + 64);
        const float m = ((j >= 0) && (j < TT)) ? 1.f : 0.f;
        a = fmaf(m, h1f[jc - H1LO][lane], a);
      }
    }
    aggbf[lt][lane] = (__bf16)a;
  }
  __syncthreads();
  if (w8 < 4) {
    const int wm = w8 >> 1, wn = w8 & 1;
    const int fr = lane & 15, fk = (lane >> 4) << 3, row0 = (lane >> 4) << 2;
    const int lhh = t0 - H1LO;
    f32x4 acc[2][2];
    #pragma unroll
    for (int f = 0; f < 2; ++f)
      #pragma unroll
      for (int g = 0; g < 2; ++g) acc[f][g] = (f32x4){0.f,0.f,0.f,0.f};
    #pragma unroll
    for (int kt = 0; kt < 4; ++kt) {
      const int ko = (kt << 5) + fk;
      bf16x8 af[2];
      #pragma unroll
      for (int f = 0; f < 2; ++f) {
        const int tr = wm*32 + f*16 + fr;
        if (tr < 55) {
          if (ko < 64) {
            af[f] = *(const bf16x8*)&aggbf[tr][ko];
          } else {
            const float* src = &h1f[tr + lhh][ko - 64];
            const float4 u0 = ((const float4*)src)[0];
            const float4 u1 = ((const float4*)src)[1];
            af[f] = (bf16x8){(__bf16)u0.x,(__bf16)u0.y,(__bf16)u0.z,(__bf16)u0.w,
                             (__bf16)u1.x,(__bf16)u1.y,(__bf16)u1.z,(__bf16)u1.w};
          }
        } else af[f] = (bf16x8){0,0,0,0,0,0,0,0};
      }
      bf16x8 bfv[2];
      #pragma unroll
      for (int g = 0; g < 2; ++g) {
        const int rb_ = wn*32 + g*16 + fr;
        bfv[g] = *(const bf16x8*)(Wgcimg + rb_*128 + (((ko >> 3) ^ (rb_ & 7)) << 3));
      }
      #pragma unroll
      for (int f = 0; f < 2; ++f)
        #pragma unroll
        for (int g = 0; g < 2; ++g)
          acc[f][g] = __builtin_amdgcn_mfma_f32_16x16x32_bf16(af[f], bfv[g], acc[f][g], 0, 0, 0);
    }
    #pragma unroll
    for (int g = 0; g < 2; ++g) {
      const int col = wn*32 + g*16 + fr;
      const float bv = brel[col];
      #pragma unroll
      for (int f = 0; f < 2; ++f) {
        const int tr0 = wm*32 + f*16 + row0;
        #pragma unroll
        for (int r2 = 0; r2 < 4; ++r2) {
          const int tr = tr0 + r2;
          if (tr < 55) {
            const int t = t0 + tr;
            h2[((size_t)t * BBD + b) * 64 + col] = (__bf16)(acc[f][g][r2] + bv);
          }
        }
      }
    }
  }
}

// ---------------------------------------------------------------------------
// attn_fused: MFMA matching attention + hidden GEMM + logits + log_softmax.
// Single bf16 Xq plane (stride 264). att never leaves LDS.
// ---------------------------------------------------------------------------
__global__ __launch_bounds__(448) void attn_fused_k(
    const __bf16* __restrict__ x, const __bf16* __restrict__ h2,
    const __bf16* __restrict__ Xq, const __bf16* __restrict__ Wlimg,
    const float* __restrict__ bl, const float* __restrict__ Wsm,
    const float* __restrict__ bsm, float* __restrict__ out)
{
  __shared__ __align__(16) __bf16 Msh [TT ][272];
  __shared__ __align__(16) __bf16 MTsh[264][136];
  __shared__ __align__(16) __bf16 Ash [112][136];
  const int b = blockIdx.x;
  const int tid = threadIdx.x;

  for (int idx = tid; idx < TT * 66; idx += 448) {
    const int s = idx / 66, c4 = idx % 66;
    const size_t node = (size_t)s * BBD + b;
    bf16x4 pk;
    if (c4 < 50) pk = *(const bf16x4*)&x [node * 200 + (c4 << 2)];
    else         pk = *(const bf16x4*)&h2[node * 64 + ((c4 - 50) << 2)];
    *(bf16x4*)&Msh[s][c4 << 2] = pk;
    const int d = c4 << 2;
    MTsh[d+0][s] = pk[0]; MTsh[d+1][s] = pk[1];
    MTsh[d+2][s] = pk[2]; MTsh[d+3][s] = pk[3];
  }
  for (int idx = tid; idx < 264 * 26; idx += 448) MTsh[idx / 26][110 + idx % 26] = (__bf16)0.f;
  for (int idx = tid; idx < 112 * 24; idx += 448) Ash[idx / 24][112 + idx % 24] = (__bf16)0.f;
  __syncthreads();

  const int wid = tid >> 6, lane = tid & 63;
  const int t0 = wid << 4;
  const int fr = lane & 15;
  const int g  = lane >> 4;
  const int fk = g << 3;
  const int row0 = g << 2;

  // ---- S = Xq * M^T (single bf16 plane) ----
  f32x4 sacc[7];
  #pragma unroll
  for (int st = 0; st < 7; ++st) sacc[st] = (f32x4){0.f,0.f,0.f,0.f};
  const int trow = t0 + fr;
  const size_t arow = ((size_t)(trow < TT ? trow : TT - 1) * BBD + b) * 264;
  for (int kst = 0; kst < 9; ++kst) {
    const int k0 = kst << 5;
    bf16x8 aq;
    if (kst < 8 || fk == 0) aq = *(const bf16x8*)&Xq[arow + k0 + fk];
    else aq = (bf16x8){0,0,0,0,0,0,0,0};
    #pragma unroll
    for (int st = 0; st < 7; ++st) {
      bf16x8 bq;
      if (kst < 8) bq = *(const bf16x8*)&Msh[st*16 + fr][k0 + fk];
      else bq = (fk == 0) ? *(const bf16x8*)&Msh[st*16 + fr][256]
                          : (bf16x8){0,0,0,0,0,0,0,0};
      sacc[st] = __builtin_amdgcn_mfma_f32_16x16x32_bf16(aq, bq, sacc[st], 0, 0, 0);
    }
  }

  // ---- tanh + softmax -> Ash ----
  #pragma unroll
  for (int r = 0; r < 4; ++r) {
    float tv[7];
    #pragma unroll
    for (int st = 0; st < 7; ++st) {
      const float e2 = __expf(2.f * sacc[st][r]);
      tv[st] = 1.f - 2.f / (e2 + 1.f);
    }
    if (fr >= 14) tv[6] = -3.0e38f;
    float mx = fmaxf(fmaxf(fmaxf(tv[0],tv[1]), fmaxf(tv[2],tv[3])),
                     fmaxf(fmaxf(tv[4],tv[5]), tv[6]));
    #pragma unroll
    for (int o = 8; o >= 1; o >>= 1) mx = fmaxf(mx, __shfl_xor(mx, o, 16));
    float e[7], sum = 0.f;
    #pragma unroll
    for (int st = 0; st < 7; ++st) { e[st] = __expf(tv[st] - mx); sum += e[st]; }
    #pragma unroll
    for (int o = 8; o >= 1; o >>= 1) sum += __shfl_xor(sum, o, 16);
    const float inv = 1.f / sum;
    const int tr = t0 + (g << 2) + r;
    #pragma unroll
    for (int st = 0; st < 7; ++st) Ash[tr][st*16 + fr] = (__bf16)(e[st] * inv);
  }
  __syncthreads();     // all Msh reads done; Ash ready

  // ---- PV: att = alpha * M -> attsh (overlays Msh) ----
  __bf16 (*attsh)[272] = Msh;
  const int tr2 = t0 + (g << 2);
  for (int dt = 0; dt < 17; ++dt) {
    const int d0 = dt << 4;
    f32x4 pacc = (f32x4){0.f,0.f,0.f,0.f};
    #pragma unroll
    for (int kst = 0; kst < 4; ++kst) {
      const int k0 = kst << 5;
      const bf16x8 pa = *(const bf16x8*)&Ash [t0 + fr][k0 + fk];
      const bf16x8 pb = *(const bf16x8*)&MTsh[d0 + fr][k0 + fk];
      pacc = __builtin_amdgcn_mfma_f32_16x16x32_bf16(pa, pb, pacc, 0, 0, 0);
    }
    const int col = d0 + fr;
    if (col < 264) {
      #pragma unroll
      for (int r = 0; r < 4; ++r) {
        const int t = tr2 + r;
        if (t < TT) attsh[t][col] = (__bf16)pacc[r];
      }
    }
  }
  __syncthreads();     // attsh complete; MTsh/Ash now dead

  // ---- stage Wsm into MTsh region ----
  float* Wssh = (float*)&MTsh[0][0];     // [64][8] f32 = 2 KB
  for (int i = tid; i < 512; i += 448) {
    const int k = i >> 3, cc = i & 7;
    Wssh[(k << 3) + cc] = (cc < 7) ? Wsm[k*7 + cc] : 0.f;
  }

  // ---- hidden = relu(att @ Wl + bl), per wave 16 rows x 64 cols ----
  float (*hidf)[68] = (float(*)[68])&Ash[0][0];
  f32x4 hacc[4];
  #pragma unroll
  for (int gg = 0; gg < 4; ++gg) hacc[gg] = (f32x4){0.f,0.f,0.f,0.f};
  #pragma unroll
  for (int kst = 0; kst < 9; ++kst) {
    const int ko = (kst << 5) + fk;
    const int ar = t0 + fr;
    bf16x8 af;
    if (ko < 264 && ar < TT) af = *(const bf16x8*)&attsh[ar][ko];
    else af = (bf16x8){0,0,0,0,0,0,0,0};
    #pragma unroll
    for (int gg = 0; gg < 4; ++gg) {
      const int rb_ = gg*16 + fr;
      const bf16x8 bfv = *(const bf16x8*)(Wlimg + rb_*320 + (((ko >> 3) ^ (rb_ & 7)) << 3));
      hacc[gg] = __builtin_amdgcn_mfma_f32_16x16x32_bf16(af, bfv, hacc[gg], 0, 0, 0);
    }
  }
  #pragma unroll
  for (int gg = 0; gg < 4; ++gg) {
    const int col = gg*16 + fr;
    const float bv = bl[col];
    #pragma unroll
    for (int r = 0; r < 4; ++r) {
      const int row = t0 + row0 + r;
      if (row < TT) hidf[row][col] = fmaxf(hacc[gg][r] + bv, 0.f);
    }
  }
  __syncthreads();

  // ---- logits + log_softmax: 8 lanes per row ----
  const int c = tid & 7;
  const float bc = (c < 7) ? bsm[c] : 0.f;
  #pragma unroll
  for (int p = 0; p < 2; ++p) {
    const int lr = p * 56 + (tid >> 3);
    if (lr < TT) {
      float lg = -3.0e38f;
      if (c < 7) {
        lg = bc;
        #pragma unroll
        for (int k = 0; k < 64; ++k) lg += hidf[lr][k] * Wssh[(k << 3) + c];
      }
      float mx = lg;
      #pragma unroll
      for (int o = 4; o >= 1; o >>= 1) mx = fmaxf(mx, __shfl_xor(mx, o, 8));
      float e = (c < 7) ? __expf(lg - mx) : 0.f;
      float sm = e;
      #pragma unroll
      for (int o = 4; o >= 1; o >>= 1) sm += __shfl_xor(sm, o, 8);
      if (c < 7) out[((size_t)b * TT + lr) * 7 + c] = lg - mx - __logf(sm);
    }
  }
}

// ---------------------------------------------------------------------------
extern "C" void kernel_launch(void* const* d_in, const int* in_sizes, int n_in,
                              void* d_out, int out_size, void* d_ws, size_t ws_size,
                              hipStream_t stream)
{
  const float* textf  = (const float*)d_in[0];
  const float* acouf  = (const float*)d_in[1];
  const float* visuf  = (const float*)d_in[2];
  const int*   spk    = (const int*)  d_in[3];
  const float* Wf     = (const float*)d_in[4];
  const float* bfv    = (const float*)d_in[5];
  const float* basis  = (const float*)d_in[6];
  const float* comp   = (const float*)d_in[7];
  const float* root   = (const float*)d_in[8];
  const float* brg    = (const float*)d_in[9];
  const float* Wrel   = (const float*)d_in[10];
  const float* brel   = (const float*)d_in[11];
  const float* Wroot2 = (const float*)d_in[12];
  const float* Wma    = (const float*)d_in[13];
  const float* bma    = (const float*)d_in[14];
  const float* Wl     = (const float*)d_in[15];
  const float* bl     = (const float*)d_in[16];
  const float* Wsm    = (const float*)d_in[17];
  const float* bsm    = (const float*)d_in[18];

  float* ws = (float*)d_ws;
  float*  wrels = ws;                               // @0        (115,200 f32)
  __bf16* img   = (__bf16*)(ws + 115200);           // 360,448 bf16 images
  __bf16* Ain   = (__bf16*)(ws + 295424);           // N*320 bf16
  __bf16* xb    = (__bf16*)(ws + 4801024);          // N*200 bf16
  __bf16* xr    = (__bf16*)(ws + 7617024);          // N*576 bf16
  __bf16* h2    = (__bf16*)(ws + 15727104);         // N*64 bf16
  __bf16* Xqb   = (__bf16*)(ws + 16628224);         // N*264 bf16
  float*  outp  = (float*)d_out;

  __bf16* Wfimg  = img;
  __bf16* wrimg  = img + 81920;
  __bf16* Wmaimg = img + 229376;
  __bf16* Wlimg  = img + 331776;
  __bf16* Wgcimg = img + 352256;

  wrels_k<<<450, 256, 0, stream>>>(basis, comp, root, wrels);
  prep_k<<<2048, 256, 0, stream>>>(textf, acouf, visuf, wrels, Wf, Wma, Wl,
                                   Wrel, Wroot2, Ain, img);
  bgemm_k<0,10,320,4><<<1760, 256, 0, stream>>>(Ain, nullptr, Wfimg, bfv, xb, 200, nullptr);
  bgemm_k<1,7,256,9><<<3960, 256, 0, stream>>>(xb, nullptr, wrimg, nullptr, xr, 576, spk);
  dialog_k<<<512, 512, 0, stream>>>(xr, spk, brg, Wgcimg, brel, h2);
  bgemm_k<2,9,320,5><<<2200, 256, 0, stream>>>(xb, h2, Wmaimg, bma, Xqb, 264, nullptr);
  attn_fused_k<<<256, 448, 0, stream>>>(xb, h2, Xqb, Wlimg, bl, Wsm, bsm, outp);
}

// Round 18
// 139.413 us; speedup vs baseline: 1.5429x; 1.0583x over previous
//
#include <hip/hip_runtime.h>

#define TT   110          // max_seq_len
#define BBD  256          // num dialogues
#define NND  28160        // TT*BBD
#define WIN  10

typedef __bf16 bf16x8 __attribute__((ext_vector_type(8)));
typedef __bf16 bf16x4 __attribute__((ext_vector_type(4)));
typedef float  f32x4  __attribute__((ext_vector_type(4)));

__device__ __forceinline__ int imax(int a, int b){ return a > b ? a : b; }
__device__ __forceinline__ int imin(int a, int b){ return a < b ? a : b; }

// All per-node matrices are SOURCE-MAJOR: row m = t*256 + b  (node n = b*110+t).
// Weight images (bf16, pre-swizzled per 64-col tile, row=col, KSP elems):
//   Wfimg [4][64][320] @ img+0
//   wrimg [9][64][256] @ img+81920
//   Wmaimg[5][64][320] @ img+229376
//   Wlimg [1][64][320] @ img+331776
//   Wgcimg[1][64][128] @ img+352256
// Image storage: source k-chunk c (8 bf16) stored at chunk position c^(col&7).

// ---------------------------------------------------------------------------
// K0: Wrels[r][f][h] = sum_nb comp[r][nb]*basis[nb][f][h]  (r<8); Wrels[8]=root
// ---------------------------------------------------------------------------
__global__ __launch_bounds__(256) void wrels_k(
    const float* __restrict__ basis, const float* __restrict__ comp,
    const float* __restrict__ root, float* __restrict__ wrels)
{
  int idx = blockIdx.x * 256 + threadIdx.x;        // 9*12800 = 115200
  if (idx >= 115200) return;
  int r = idx / 12800, fh = idx % 12800;
  float v;
  if (r < 8) {
    v = 0.f;
    #pragma unroll
    for (int nb = 0; nb < 30; ++nb) v += comp[r*30 + nb] * basis[nb*12800 + fh];
  } else {
    v = root[fh];
  }
  wrels[idx] = v;
}

// ---------------------------------------------------------------------------
// prep_k: build all bf16 pre-swizzled weight tile images (wrels precomputed).
// (Ain packing removed in round 18 — bgemm mode 0 reads f32 inputs directly.)
// ---------------------------------------------------------------------------
__global__ __launch_bounds__(256) void prep_k(
    const float* __restrict__ wrels, const float* __restrict__ Wf,
    const float* __restrict__ Wma, const float* __restrict__ Wl,
    const float* __restrict__ Wrel, const float* __restrict__ Wroot2,
    __bf16* __restrict__ img)
{
  constexpr int T1 = 10240;              // Wf   4*64*40
  constexpr int T2 = T1 + 18432;         // wrels 9*64*32
  constexpr int T3 = T2 + 12800;         // Wma  5*64*40
  constexpr int T4 = T3 + 2560;          // Wl   64*40
  constexpr int T5 = T4 + 1024;          // Wgc  64*16
  for (int c = blockIdx.x * 256 + threadIdx.x; c < T5; c += gridDim.x * 256) {
    bf16x8 v;
    __bf16* dst;
    if (c < T1) {
      const int r = c;
      const int cb = r / 2560, r2 = r - cb * 2560;
      const int col = r2 / 40, ch = r2 - col * 40;
      const int cs = (ch & ~7) | ((ch ^ col) & 7);
      const int gc = (cb << 6) + col;
      #pragma unroll
      for (int e = 0; e < 8; ++e) {
        const int k = (cs << 3) + e;
        v[e] = (__bf16)((k < 300 && gc < 200) ? Wf[k*200 + gc] : 0.f);
      }
      dst = img + cb * 20480 + col * 320 + (ch << 3);
    } else if (c < T2) {
      const int r = c - T1;
      const int cb = r >> 11, r2 = r & 2047;
      const int col = r2 >> 5, ch = r2 & 31;
      const int cs = (ch & ~7) | ((ch ^ col) & 7);
      #pragma unroll
      for (int e = 0; e < 8; ++e) {
        const int k = (cs << 3) + e;
        v[e] = (__bf16)((k < 200) ? wrels[cb*12800 + k*64 + col] : 0.f);
      }
      dst = img + 81920 + cb * 16384 + col * 256 + (ch << 3);
    } else if (c < T3) {
      const int r = c - T2;
      const int cb = r / 2560, r2 = r - cb * 2560;
      const int col = r2 / 40, ch = r2 - col * 40;
      const int cs = (ch & ~7) | ((ch ^ col) & 7);
      const int gc = (cb << 6) + col;
      #pragma unroll
      for (int e = 0; e < 8; ++e) {
        const int k = (cs << 3) + e;
        v[e] = (__bf16)((k < 264 && gc < 264) ? Wma[k*264 + gc] : 0.f);
      }
      dst = img + 229376 + cb * 20480 + col * 320 + (ch << 3);
    } else if (c < T4) {
      const int r = c - T3;
      const int col = r / 40, ch = r - col * 40;
      const int cs = (ch & ~7) | ((ch ^ col) & 7);
      #pragma unroll
      for (int e = 0; e < 8; ++e) {
        const int k = (cs << 3) + e;
        v[e] = (__bf16)((k < 264) ? Wl[k*64 + col] : 0.f);
      }
      dst = img + 331776 + col * 320 + (ch << 3);
    } else {
      const int r = c - T4;
      const int col = r / 16, ch = r - col * 16;
      const int cs = (ch & ~7) | ((ch ^ col) & 7);
      #pragma unroll
      for (int e = 0; e < 8; ++e) {
        const int k = (cs << 3) + e;
        v[e] = (__bf16)((k < 64) ? Wrel[k*64 + col] : Wroot2[(k-64)*64 + col]);
      }
      dst = img + 352256 + col * 128 + (ch << 3);
    }
    *(bf16x8*)dst = v;
  }
}

// ---------------------------------------------------------------------------
// bgemm: B-resident MFMA GEMM, pre-swizzled B image.
// MODE 0: A = concat(textf,acouf,visuf) f32 source-major, per-float4 select
//         (boundaries 100/200/300 are 4-aligned).
// MODE 1: A=xb bf16; spkm-masked xr writes. MODE 2: A=[xb|h2] bf16.
// ---------------------------------------------------------------------------
template<int MODE, int NK, int KSP, int NCB>
__global__ __launch_bounds__(256) void bgemm_k(
    const void* __restrict__ a0, const void* __restrict__ a1,
    const void* __restrict__ a2, const __bf16* __restrict__ Bimg,
    const float* __restrict__ bias, __bf16* __restrict__ Cv, int Ncols,
    const int* __restrict__ spkm)
{
  __shared__ __align__(16) __bf16 Bsh[64][KSP];
  const int tid = threadIdx.x;
  constexpr int NWT = 440 * NCB;
  constexpr int q = NWT >> 3;
  const int bid = blockIdx.x;
  const int w = (bid & 7) * q + (bid >> 3);          // bijective XCD swizzle
  const int m0 = (w / NCB) << 6;
  const int cb = w % NCB;
  const int n0 = cb << 6;

  { // ---- B tile: linear vector copy of pre-swizzled image ----
    const bf16x8* src = (const bf16x8*)(Bimg + (size_t)cb * (64 * KSP));
    bf16x8* dst = (bf16x8*)&Bsh[0][0];
    constexpr int NIT = (64 * KSP / 8) / 256;
    #pragma unroll
    for (int c = 0; c < NIT; ++c) dst[c * 256 + tid] = src[c * 256 + tid];
  }
  __syncthreads();

  const int wid = tid >> 6, lane = tid & 63;
  const int wm = wid >> 1, wn = wid & 1;
  const int fr = lane & 15;
  const int fk = (lane >> 4) << 3;
  const int row0 = (lane >> 4) << 2;

  f32x4 acc[2][2];
  #pragma unroll
  for (int f = 0; f < 2; ++f)
    #pragma unroll
    for (int g = 0; g < 2; ++g) acc[f][g] = (f32x4){0.f,0.f,0.f,0.f};

  #pragma unroll
  for (int kt = 0; kt < NK; ++kt) {
    const int ko = (kt << 5) + fk;
    bf16x8 af[2];
    #pragma unroll
    for (int f = 0; f < 2; ++f) {
      const int ra = m0 + wm*32 + f*16 + fr;
      if constexpr (MODE == 0) {
        const size_t ab = (size_t)ra * 100;
        float4 u[2];
        #pragma unroll
        for (int h = 0; h < 2; ++h) {
          const int g4 = ko + (h << 2);
          if (g4 < 100)      u[h] = *(const float4*)((const float*)a0 + ab + g4);
          else if (g4 < 200) u[h] = *(const float4*)((const float*)a1 + ab + g4 - 100);
          else if (g4 < 300) u[h] = *(const float4*)((const float*)a2 + ab + g4 - 200);
          else               u[h] = make_float4(0.f,0.f,0.f,0.f);
        }
        af[f] = (bf16x8){(__bf16)u[0].x,(__bf16)u[0].y,(__bf16)u[0].z,(__bf16)u[0].w,
                         (__bf16)u[1].x,(__bf16)u[1].y,(__bf16)u[1].z,(__bf16)u[1].w};
      } else if constexpr (MODE == 2) {
        af[f] = (ko < 200)
              ? *(const bf16x8*)((const __bf16*)a0 + (size_t)ra*200 + ko)
              : *(const bf16x8*)((const __bf16*)a1 + (size_t)ra*64 + (ko - 200));
      } else {
        af[f] = *(const bf16x8*)((const __bf16*)a0 + (size_t)ra*200 + ko);
      }
    }
    bf16x8 bfv[2];
    #pragma unroll
    for (int g = 0; g < 2; ++g) {
      const int rb_ = wn*32 + g*16 + fr;
      bfv[g] = *(const bf16x8*)&Bsh[rb_][(((ko >> 3) ^ (rb_ & 7)) << 3)];
    }
    #pragma unroll
    for (int f = 0; f < 2; ++f)
      #pragma unroll
      for (int g = 0; g < 2; ++g)
        acc[f][g] = __builtin_amdgcn_mfma_f32_16x16x32_bf16(af[f], bfv[g], acc[f][g], 0, 0, 0);
  }

  // ---- epilogue: D col=lane&15, row=(lane>>4)*4+reg ----
  #pragma unroll
  for (int f = 0; f < 2; ++f) {
    const int gm0 = m0 + wm*32 + f*16 + row0;
    int sp[4];
    if constexpr (MODE == 1) {
      #pragma unroll
      for (int r2 = 0; r2 < 4; ++r2) sp[r2] = spkm[gm0 + r2];
    }
    #pragma unroll
    for (int g = 0; g < 2; ++g) {
      const int col = n0 + wn*32 + g*16 + fr;
      if (col < Ncols) {
        const float bv = bias ? bias[col] : 0.f;
        #pragma unroll
        for (int r2 = 0; r2 < 4; ++r2) {
          const float v = acc[f][g][r2] + bv;
          const int gm = gm0 + r2;
          bool dow = true;
          if constexpr (MODE == 1) dow = (cb == 8) || ((cb >> 2) == sp[r2]);
          if (dow) Cv[(size_t)gm * Ncols + col] = (__bf16)v;
        }
      }
    }
  }
}

// ---------------------------------------------------------------------------
// dialog_k: fused RGCN mean-agg + window-sum + GraphConv GEMM (round-14 cfg).
// ---------------------------------------------------------------------------
__global__ __launch_bounds__(512) void dialog_k(
    const __bf16* __restrict__ xr, const int* __restrict__ spk,
    const float* __restrict__ brg, const __bf16* __restrict__ Wgcimg,
    const float* __restrict__ brel, __bf16* __restrict__ h2)
{
  __shared__ __align__(16) __bf16 Xsh[75][320];
  __shared__ float  h1f[65][68];
  __shared__ __align__(16) __bf16 aggbf[56][72];
  __shared__ int ssp[TT];
  __shared__ int pc[TT + 1];
  const int bid = blockIdx.x;
  const int b = bid >> 1, half = bid & 1;
  const int t0   = half ? 55 : 0;
  const int H1LO = half ? 45 : 0;
  const int XLO  = half ? 35 : 0;
  const int tid = threadIdx.x;
  if (tid < TT) ssp[tid] = spk[tid * BBD + b];
  __syncthreads();
  if (tid < 64) {
    int v = (tid < TT) ? ssp[tid] : 0;
    #pragma unroll
    for (int o = 1; o < 64; o <<= 1) { const int u = __shfl_up(v, o); if (tid >= o) v += u; }
    pc[tid + 1] = v;
    const int tot = __shfl(v, 63);
    int v2 = (tid + 64 < TT) ? ssp[tid + 64] : 0;
    #pragma unroll
    for (int o = 1; o < 64; o <<= 1) { const int u = __shfl_up(v2, o); if (tid >= o) v2 += u; }
    if (tid + 64 < TT) pc[tid + 65] = tot + v2;
    if (tid == 0) pc[0] = 0;
  }
  for (int i = tid << 3; i < 75 * 320; i += 512 << 3) {
    const int xl = i / 320, off = i - xl * 320;
    const int j = XLO + xl;
    const size_t base = ((size_t)j * BBD + b) * 576;
    const int col = (off < 256) ? ((ssp[j] << 8) + off) : (256 + off);
    *(bf16x8*)&Xsh[xl][off] = *(const bf16x8*)&xr[base + col];
  }
  __syncthreads();
  const int w8 = tid >> 6, lane = tid & 63;
  const float bias = brg[lane];
  for (int lh = w8; lh < 65; lh += 8) {
    const int t = H1LO + lh;
    const int si2 = ssp[t] << 1;
    const int jlo = imax(t - WIN, 0), jhi = imin(t + WIN, TT - 1);
    const int n1d0 = pc[t] - pc[jlo];
    const int n0d0 = (t - jlo) - n1d0;
    const int n1d1 = pc[jhi + 1] - pc[t];
    const int n0d1 = (jhi - t + 1) - n1d1;
    const float r00 = 1.f / (float)imax(n0d0, 1);
    const float r10 = 1.f / (float)imax(n1d0, 1);
    const float r01 = 1.f / (float)imax(n0d1, 1);
    const float r11 = 1.f / (float)imax(n1d1, 1);
    float a = 0.f;
    if (t >= WIN && t < TT - WIN) {
      #pragma unroll
      for (int dj = -WIN; dj <= WIN; ++dj) {
        const int j = t + dj;
        const float v = (float)Xsh[j - XLO][((si2 + ((dj >= 0) ? 1 : 0)) << 6) + lane];
        const float w = (dj >= 0) ? (ssp[j] ? r11 : r01) : (ssp[j] ? r10 : r00);
        a = fmaf(w, v, a);
      }
    } else {
      #pragma unroll
      for (int dj = -WIN; dj <= WIN; ++dj) {
        const int j = t + dj;
        const int jc = imin(imax(j, XLO), XLO + 74);
        const float v = (float)Xsh[jc - XLO][((si2 + ((dj >= 0) ? 1 : 0)) << 6) + lane];
        float w = (dj >= 0) ? (ssp[jc] ? r11 : r01) : (ssp[jc] ? r10 : r00);
        if (j < 0 || j >= TT) w = 0.f;
        a = fmaf(w, v, a);
      }
    }
    a += (float)Xsh[t - XLO][256 + lane] + bias;
    h1f[lh][lane] = a;
  }
  __syncthreads();
  for (int lt = w8; lt < 55; lt += 8) {
    const int t = t0 + lt;
    float a = 0.f;
    if (t >= WIN && t < TT - WIN) {
      #pragma unroll
      for (int dj = -WIN; dj <= WIN; ++dj)
        a += h1f[t + dj - H1LO][lane];
    } else {
      #pragma unroll
      for (int dj = -WIN; dj <= WIN; ++dj) {
        const int j = t + dj;
        const int jc = imin(imax(j, H1LO), H1LO + 64);
        const float m = ((j >= 0) && (j < TT)) ? 1.f : 0.f;
        a = fmaf(m, h1f[jc - H1LO][lane], a);
      }
    }
    aggbf[lt][lane] = (__bf16)a;
  }
  __syncthreads();
  if (w8 < 4) {
    const int wm = w8 >> 1, wn = w8 & 1;
    const int fr = lane & 15, fk = (lane >> 4) << 3, row0 = (lane >> 4) << 2;
    const int lhh = t0 - H1LO;
    f32x4 acc[2][2];
    #pragma unroll
    for (int f = 0; f < 2; ++f)
      #pragma unroll
      for (int g = 0; g < 2; ++g) acc[f][g] = (f32x4){0.f,0.f,0.f,0.f};
    #pragma unroll
    for (int kt = 0; kt < 4; ++kt) {
      const int ko = (kt << 5) + fk;
      bf16x8 af[2];
      #pragma unroll
      for (int f = 0; f < 2; ++f) {
        const int tr = wm*32 + f*16 + fr;
        if (tr < 55) {
          if (ko < 64) {
            af[f] = *(const bf16x8*)&aggbf[tr][ko];
          } else {
            const float* src = &h1f[tr + lhh][ko - 64];
            const float4 u0 = ((const float4*)src)[0];
            const float4 u1 = ((const float4*)src)[1];
            af[f] = (bf16x8){(__bf16)u0.x,(__bf16)u0.y,(__bf16)u0.z,(__bf16)u0.w,
                             (__bf16)u1.x,(__bf16)u1.y,(__bf16)u1.z,(__bf16)u1.w};
          }
        } else af[f] = (bf16x8){0,0,0,0,0,0,0,0};
      }
      bf16x8 bfv[2];
      #pragma unroll
      for (int g = 0; g < 2; ++g) {
        const int rb_ = wn*32 + g*16 + fr;
        bfv[g] = *(const bf16x8*)(Wgcimg + rb_*128 + (((ko >> 3) ^ (rb_ & 7)) << 3));
      }
      #pragma unroll
      for (int f = 0; f < 2; ++f)
        #pragma unroll
        for (int g = 0; g < 2; ++g)
          acc[f][g] = __builtin_amdgcn_mfma_f32_16x16x32_bf16(af[f], bfv[g], acc[f][g], 0, 0, 0);
    }
    #pragma unroll
    for (int g = 0; g < 2; ++g) {
      const int col = wn*32 + g*16 + fr;
      const float bv = brel[col];
      #pragma unroll
      for (int f = 0; f < 2; ++f) {
        const int tr0 = wm*32 + f*16 + row0;
        #pragma unroll
        for (int r2 = 0; r2 < 4; ++r2) {
          const int tr = tr0 + r2;
          if (tr < 55) {
            const int t = t0 + tr;
            h2[((size_t)t * BBD + b) * 64 + col] = (__bf16)(acc[f][g][r2] + bv);
          }
        }
      }
    }
  }
}

// ---------------------------------------------------------------------------
// attn_fused: MFMA matching attention + hidden GEMM + logits + log_softmax.
// ---------------------------------------------------------------------------
__global__ __launch_bounds__(448) void attn_fused_k(
    const __bf16* __restrict__ x, const __bf16* __restrict__ h2,
    const __bf16* __restrict__ Xq, const __bf16* __restrict__ Wlimg,
    const float* __restrict__ bl, const float* __restrict__ Wsm,
    const float* __restrict__ bsm, float* __restrict__ out)
{
  __shared__ __align__(16) __bf16 Msh [TT ][272];
  __shared__ __align__(16) __bf16 MTsh[264][136];
  __shared__ __align__(16) __bf16 Ash [112][136];
  const int b = blockIdx.x;
  const int tid = threadIdx.x;

  for (int idx = tid; idx < TT * 66; idx += 448) {
    const int s = idx / 66, c4 = idx % 66;
    const size_t node = (size_t)s * BBD + b;
    bf16x4 pk;
    if (c4 < 50) pk = *(const bf16x4*)&x [node * 200 + (c4 << 2)];
    else         pk = *(const bf16x4*)&h2[node * 64 + ((c4 - 50) << 2)];
    *(bf16x4*)&Msh[s][c4 << 2] = pk;
    const int d = c4 << 2;
    MTsh[d+0][s] = pk[0]; MTsh[d+1][s] = pk[1];
    MTsh[d+2][s] = pk[2]; MTsh[d+3][s] = pk[3];
  }
  for (int idx = tid; idx < 264 * 26; idx += 448) MTsh[idx / 26][110 + idx % 26] = (__bf16)0.f;
  for (int idx = tid; idx < 112 * 24; idx += 448) Ash[idx / 24][112 + idx % 24] = (__bf16)0.f;
  __syncthreads();

  const int wid = tid >> 6, lane = tid & 63;
  const int t0 = wid << 4;
  const int fr = lane & 15;
  const int g  = lane >> 4;
  const int fk = g << 3;
  const int row0 = g << 2;

  // ---- S = Xq * M^T (single bf16 plane) ----
  f32x4 sacc[7];
  #pragma unroll
  for (int st = 0; st < 7; ++st) sacc[st] = (f32x4){0.f,0.f,0.f,0.f};
  const int trow = t0 + fr;
  const size_t arow = ((size_t)(trow < TT ? trow : TT - 1) * BBD + b) * 264;
  for (int kst = 0; kst < 9; ++kst) {
    const int k0 = kst << 5;
    bf16x8 aq;
    if (kst < 8 || fk == 0) aq = *(const bf16x8*)&Xq[arow + k0 + fk];
    else aq = (bf16x8){0,0,0,0,0,0,0,0};
    #pragma unroll
    for (int st = 0; st < 7; ++st) {
      bf16x8 bq;
      if (kst < 8) bq = *(const bf16x8*)&Msh[st*16 + fr][k0 + fk];
      else bq = (fk == 0) ? *(const bf16x8*)&Msh[st*16 + fr][256]
                          : (bf16x8){0,0,0,0,0,0,0,0};
      sacc[st] = __builtin_amdgcn_mfma_f32_16x16x32_bf16(aq, bq, sacc[st], 0, 0, 0);
    }
  }

  // ---- tanh + softmax -> Ash ----
  #pragma unroll
  for (int r = 0; r < 4; ++r) {
    float tv[7];
    #pragma unroll
    for (int st = 0; st < 7; ++st) {
      const float e2 = __expf(2.f * sacc[st][r]);
      tv[st] = 1.f - 2.f / (e2 + 1.f);
    }
    if (fr >= 14) tv[6] = -3.0e38f;
    float mx = fmaxf(fmaxf(fmaxf(tv[0],tv[1]), fmaxf(tv[2],tv[3])),
                     fmaxf(fmaxf(tv[4],tv[5]), tv[6]));
    #pragma unroll
    for (int o = 8; o >= 1; o >>= 1) mx = fmaxf(mx, __shfl_xor(mx, o, 16));
    float e[7], sum = 0.f;
    #pragma unroll
    for (int st = 0; st < 7; ++st) { e[st] = __expf(tv[st] - mx); sum += e[st]; }
    #pragma unroll
    for (int o = 8; o >= 1; o >>= 1) sum += __shfl_xor(sum, o, 16);
    const float inv = 1.f / sum;
    const int tr = t0 + (g << 2) + r;
    #pragma unroll
    for (int st = 0; st < 7; ++st) Ash[tr][st*16 + fr] = (__bf16)(e[st] * inv);
  }
  __syncthreads();

  // ---- PV: att = alpha * M -> attsh (overlays Msh) ----
  __bf16 (*attsh)[272] = Msh;
  const int tr2 = t0 + (g << 2);
  for (int dt = 0; dt < 17; ++dt) {
    const int d0 = dt << 4;
    f32x4 pacc = (f32x4){0.f,0.f,0.f,0.f};
    #pragma unroll
    for (int kst = 0; kst < 4; ++kst) {
      const int k0 = kst << 5;
      const bf16x8 pa = *(const bf16x8*)&Ash [t0 + fr][k0 + fk];
      const bf16x8 pb = *(const bf16x8*)&MTsh[d0 + fr][k0 + fk];
      pacc = __builtin_amdgcn_mfma_f32_16x16x32_bf16(pa, pb, pacc, 0, 0, 0);
    }
    const int col = d0 + fr;
    if (col < 264) {
      #pragma unroll
      for (int r = 0; r < 4; ++r) {
        const int t = tr2 + r;
        if (t < TT) attsh[t][col] = (__bf16)pacc[r];
      }
    }
  }
  __syncthreads();

  // ---- stage Wsm into MTsh region ----
  float* Wssh = (float*)&MTsh[0][0];
  for (int i = tid; i < 512; i += 448) {
    const int k = i >> 3, cc = i & 7;
    Wssh[(k << 3) + cc] = (cc < 7) ? Wsm[k*7 + cc] : 0.f;
  }

  // ---- hidden = relu(att @ Wl + bl), per wave 16 rows x 64 cols ----
  float (*hidf)[68] = (float(*)[68])&Ash[0][0];
  f32x4 hacc[4];
  #pragma unroll
  for (int gg = 0; gg < 4; ++gg) hacc[gg] = (f32x4){0.f,0.f,0.f,0.f};
  #pragma unroll
  for (int kst = 0; kst < 9; ++kst) {
    const int ko = (kst << 5) + fk;
    const int ar = t0 + fr;
    bf16x8 af;
    if (ko < 264 && ar < TT) af = *(const bf16x8*)&attsh[ar][ko];
    else af = (bf16x8){0,0,0,0,0,0,0,0};
    #pragma unroll
    for (int gg = 0; gg < 4; ++gg) {
      const int rb_ = gg*16 + fr;
      const bf16x8 bfv = *(const bf16x8*)(Wlimg + rb_*320 + (((ko >> 3) ^ (rb_ & 7)) << 3));
      hacc[gg] = __builtin_amdgcn_mfma_f32_16x16x32_bf16(af, bfv, hacc[gg], 0, 0, 0);
    }
  }
  #pragma unroll
  for (int gg = 0; gg < 4; ++gg) {
    const int col = gg*16 + fr;
    const float bv = bl[col];
    #pragma unroll
    for (int r = 0; r < 4; ++r) {
      const int row = t0 + row0 + r;
      if (row < TT) hidf[row][col] = fmaxf(hacc[gg][r] + bv, 0.f);
    }
  }
  __syncthreads();

  // ---- logits + log_softmax: 8 lanes per row ----
  const int c = tid & 7;
  const float bc = (c < 7) ? bsm[c] : 0.f;
  #pragma unroll
  for (int p = 0; p < 2; ++p) {
    const int lr = p * 56 + (tid >> 3);
    if (lr < TT) {
      float lg = -3.0e38f;
      if (c < 7) {
        lg = bc;
        #pragma unroll
        for (int k = 0; k < 64; ++k) lg += hidf[lr][k] * Wssh[(k << 3) + c];
      }
      float mx = lg;
      #pragma unroll
      for (int o = 4; o >= 1; o >>= 1) mx = fmaxf(mx, __shfl_xor(mx, o, 8));
      float e = (c < 7) ? __expf(lg - mx) : 0.f;
      float sm = e;
      #pragma unroll
      for (int o = 4; o >= 1; o >>= 1) sm += __shfl_xor(sm, o, 8);
      if (c < 7) out[((size_t)b * TT + lr) * 7 + c] = lg - mx - __logf(sm);
    }
  }
}

// ---------------------------------------------------------------------------
extern "C" void kernel_launch(void* const* d_in, const int* in_sizes, int n_in,
                              void* d_out, int out_size, void* d_ws, size_t ws_size,
                              hipStream_t stream)
{
  const float* textf  = (const float*)d_in[0];
  const float* acouf  = (const float*)d_in[1];
  const float* visuf  = (const float*)d_in[2];
  const int*   spk    = (const int*)  d_in[3];
  const float* Wf     = (const float*)d_in[4];
  const float* bfv    = (const float*)d_in[5];
  const float* basis  = (const float*)d_in[6];
  const float* comp   = (const float*)d_in[7];
  const float* root   = (const float*)d_in[8];
  const float* brg    = (const float*)d_in[9];
  const float* Wrel   = (const float*)d_in[10];
  const float* brel   = (const float*)d_in[11];
  const float* Wroot2 = (const float*)d_in[12];
  const float* Wma    = (const float*)d_in[13];
  const float* bma    = (const float*)d_in[14];
  const float* Wl     = (const float*)d_in[15];
  const float* bl     = (const float*)d_in[16];
  const float* Wsm    = (const float*)d_in[17];
  const float* bsm    = (const float*)d_in[18];

  float* ws = (float*)d_ws;
  float*  wrels = ws;                               // @0        (115,200 f32)
  __bf16* img   = (__bf16*)(ws + 115200);           // 360,448 bf16 images
  __bf16* xb    = (__bf16*)(ws + 4801024);          // N*200 bf16
  __bf16* xr    = (__bf16*)(ws + 7617024);          // N*576 bf16
  __bf16* h2    = (__bf16*)(ws + 15727104);         // N*64 bf16
  __bf16* Xqb   = (__bf16*)(ws + 16628224);         // N*264 bf16
  float*  outp  = (float*)d_out;

  __bf16* Wfimg  = img;
  __bf16* wrimg  = img + 81920;
  __bf16* Wmaimg = img + 229376;
  __bf16* Wlimg  = img + 331776;
  __bf16* Wgcimg = img + 352256;

  wrels_k<<<450, 256, 0, stream>>>(basis, comp, root, wrels);
  prep_k<<<176, 256, 0, stream>>>(wrels, Wf, Wma, Wl, Wrel, Wroot2, img);
  bgemm_k<0,10,320,4><<<1760, 256, 0, stream>>>(textf, acouf, visuf, Wfimg, bfv, xb, 200, nullptr);
  bgemm_k<1,7,256,9><<<3960, 256, 0, stream>>>(xb, nullptr, nullptr, wrimg, nullptr, xr, 576, spk);
  dialog_k<<<512, 512, 0, stream>>>(xr, spk, brg, Wgcimg, brel, h2);
  bgemm_k<2,9,320,5><<<2200, 256, 0, stream>>>(xb, h2, nullptr, Wmaimg, bma, Xqb, 264, nullptr);
  attn_fused_k<<<256, 448, 0, stream>>>(xb, h2, Xqb, Wlimg, bl, Wsm, bsm, outp);
}